// Round 13
// baseline (33.348 us; speedup 1.0000x reference)
//
#include <hip/hip_runtime.h>
#include <float.h>

#define BATCH 8
#define NPTS 4096
#define BLK 256
#define OCT 512               // adv cols per block
#define NOCT 8                // col octants
#define NRG 16                // row groups
#define NTILE (OCT / 32)      // 16 col-tiles per block

typedef __attribute__((ext_vector_type(8))) short short8;      // 8 bf16
typedef __attribute__((ext_vector_type(16))) float floatx16;   // 32x32 MFMA acc

union U4S8 { uint4 u; short8 s; };

// round-to-nearest-even f32 -> bf16 bits
__device__ inline unsigned short f2bf(float f) {
    unsigned u = __float_as_uint(f);
    return (unsigned short)((u + 0x7FFFu + ((u >> 16) & 1u)) >> 16);
}
__device__ inline float bf2f(unsigned short h) {
    return __uint_as_float(((unsigned)h) << 16);
}
__device__ inline unsigned flag_token(int i) {
    return 0x9E3779B9u * (unsigned)(i + 7);   // never 0xAAAAAAAA poison
}

// ---------------------------------------------------------------------------
// Symmetric kernel: d1 and d2 come from the SAME D = dist(ori, adv) matrix
// (row-min -> d1, col-min -> d2), so D is computed ONCE per batch --
// half the MFMAs/staging of rounds 7-12.
// Grid = 1024 = (b(8), rowgroup(16), octant(8)); block = 256 ori-rows x
// 512 adv-cols; round 10's best config (__launch_bounds__(256,4), in-loop
// cndmask B-frag rebuild). K=16 hi/lo bf16 encoding (verified rounds 7-12,
// absmax 0.0) folds |q|^2 + |t|^2 - 2q.t into one mfma_f32_32x32x16_bf16.
// Per tile: 2 MFMAs (2 row-bands); row-mins accumulate in regs across tiles;
// col-min = reg-min + shfl_xor(32) (lanes l,l+32 share a column), staged in
// cmin[wave][512] and min-reduced across the 4 waves at block end.
// rpart[b][oct][row] and cpart[b][rg][col] each written exactly once.
// ---------------------------------------------------------------------------
__global__ __launch_bounds__(BLK, 4) void chamfer_sym(
        const float* __restrict__ ori, const float* __restrict__ adv,
        float* __restrict__ rpart, float* __restrict__ cpart) {
    __shared__ uint4 sm[OCT];        // 8 KB packed adv targets
    __shared__ float cmin[4][OCT];   // 8 KB per-wave col mins

    int bx = blockIdx.x;               // 0..1023
    int oct = bx & 7;
    int rowgroup = (bx >> 3) & 15;
    int b = bx >> 7;                   // 0..7

    // ---- stage this octant's 512 adv points, packed hi/lo ----
    {
        const float* tx = adv + (b * 3 + 0) * NPTS;
        const float* ty = adv + (b * 3 + 1) * NPTS;
        const float* tz = adv + (b * 3 + 2) * NPTS;
        #pragma unroll
        for (int i = 0; i < OCT / BLK; ++i) {
            int p = threadIdx.x + i * BLK;
            int m = oct * OCT + p;
            float x = tx[m], y = ty[m], z = tz[m];
            float n2 = fmaf(x, x, fmaf(y, y, z * z));
            unsigned short hx = f2bf(x), hy = f2bf(y), hz = f2bf(z);
            unsigned short lx = f2bf(x - bf2f(hx));
            unsigned short ly = f2bf(y - bf2f(hy));
            unsigned short lz = f2bf(z - bf2f(hz));
            unsigned short h2 = f2bf(n2);
            unsigned short l2 = f2bf(n2 - bf2f(h2));
            uint4 u;
            u.x = (unsigned)hx | ((unsigned)hy << 16);
            u.y = (unsigned)hz | ((unsigned)lx << 16);
            u.z = (unsigned)ly | ((unsigned)lz << 16);
            u.w = (unsigned)h2 | ((unsigned)l2 << 16);
            sm[p] = u;
        }
    }

    // ---- per-wave A fragments: 2 bands of 32 ori rows ----
    int w = threadIdx.x >> 6;          // wave 0..3
    int l = threadIdx.x & 63;
    int lrow = l & 31;
    int kh = l >> 5;

    short8 afrag[2];
    #pragma unroll
    for (int bi = 0; bi < 2; ++bi) {
        int q = rowgroup * 256 + (w * 2 + bi) * 32 + lrow;
        float x = ori[(b * 3 + 0) * NPTS + q];
        float y = ori[(b * 3 + 1) * NPTS + q];
        float z = ori[(b * 3 + 2) * NPTS + q];
        float n2 = fmaf(x, x, fmaf(y, y, z * z));
        unsigned short hx = f2bf(x), hy = f2bf(y), hz = f2bf(z);
        unsigned short lx = f2bf(x - bf2f(hx));
        unsigned short ly = f2bf(y - bf2f(hy));
        unsigned short lz = f2bf(z - bf2f(hz));
        unsigned short h2 = f2bf(n2);
        unsigned short l2 = f2bf(n2 - bf2f(h2));
        unsigned short mhx = f2bf(-2.0f * bf2f(hx));
        unsigned short mhy = f2bf(-2.0f * bf2f(hy));
        unsigned short mhz = f2bf(-2.0f * bf2f(hz));
        unsigned short mlx = f2bf(-2.0f * bf2f(lx));
        unsigned short mly = f2bf(-2.0f * bf2f(ly));
        unsigned short mlz = f2bf(-2.0f * bf2f(lz));
        const unsigned short one = 0x3F80;
        union { unsigned short us[8]; short8 s8; } A;
        if (kh == 0) {
            A.us[0] = mhx; A.us[1] = mhy; A.us[2] = mhz;
            A.us[3] = mhx; A.us[4] = mhy; A.us[5] = mhz;
            A.us[6] = one; A.us[7] = one;
        } else {
            A.us[0] = mlx; A.us[1] = mly; A.us[2] = mlz;
            A.us[3] = h2;  A.us[4] = l2;
            A.us[5] = 0;   A.us[6] = 0;   A.us[7] = 0;
        }
        afrag[bi] = A.s8;
    }
    __syncthreads();

    floatx16 zero, rmn0, rmn1;
    #pragma unroll
    for (int r = 0; r < 16; ++r) { zero[r] = 0.0f; rmn0[r] = FLT_MAX; rmn1[r] = FLT_MAX; }

    bool hi = (kh == 1);
    int col = lrow;

    // ---- tile-serial loop (ping-pong raw load; 2 MFMAs in flight) ----
    {
        uint4 cur = sm[col];
        #pragma unroll 1
        for (int t = 0; t < NTILE; ++t) {
            uint4 nxt = sm[(((t + 1) & (NTILE - 1)) << 5) + col];
            U4S8 f;
            f.u.x = cur.x;
            f.u.y = hi ? ((cur.y & 0xFFFFu) | 0x3F800000u) : cur.y;
            f.u.z = hi ? 0x00003F80u : cur.z;
            f.u.w = hi ? 0u : cur.w;
            floatx16 a0 = __builtin_amdgcn_mfma_f32_32x32x16_bf16(afrag[0], f.s, zero, 0, 0, 0);
            floatx16 a1 = __builtin_amdgcn_mfma_f32_32x32x16_bf16(afrag[1], f.s, zero, 0, 0, 0);
            float cm = fminf(a0[0], a1[0]);
            #pragma unroll
            for (int r = 0; r < 16; ++r) {
                rmn0[r] = fminf(rmn0[r], a0[r]);
                rmn1[r] = fminf(rmn1[r], a1[r]);
                if (r) cm = fminf(cm, fminf(a0[r], a1[r]));   // -> v_min3_f32
            }
            cm = fminf(cm, __shfl_xor(cm, 32));   // lanes l, l+32 share col
            if (l < 32) cmin[w][(t << 5) + l] = cm;
            cur = nxt;
        }
    }

    // ---- row epilogue: butterfly min over 32 cols; write row partials ----
    #pragma unroll
    for (int r = 0; r < 16; ++r) {
        float v0 = rmn0[r], v1 = rmn1[r];
        #pragma unroll
        for (int m = 1; m <= 16; m <<= 1) {
            v0 = fminf(v0, __shfl_xor(v0, m));
            v1 = fminf(v1, __shfl_xor(v1, m));
        }
        rmn0[r] = v0; rmn1[r] = v1;
    }
    if (lrow == 0) {
        // C/D row = (r&3) + 8*(r>>2) + 4*kh (verified m74/m101, rounds 7-12)
        float* base = rpart + (((size_t)(b * NOCT + oct)) << 12)
                    + rowgroup * 256 + kh * 4;
        float* d0 = base + (w * 2 + 0) * 32;
        float* d1 = base + (w * 2 + 1) * 32;
        #pragma unroll
        for (int r = 0; r < 16; ++r) {
            int off = (r & 3) + 8 * (r >> 2);
            d0[off] = rmn0[r];
            d1[off] = rmn1[r];
        }
    }

    // ---- col epilogue: min across the 4 waves' planes ----
    __syncthreads();
    {
        int t = threadIdx.x;
        #pragma unroll
        for (int i = 0; i < OCT / BLK; ++i) {
            int c = t + i * BLK;
            float m = fminf(fminf(cmin[0][c], cmin[1][c]),
                            fminf(cmin[2][c], cmin[3][c]));
            cpart[(((size_t)(b * NRG + rowgroup)) << 12) + oct * OCT + c] = m;
        }
    }
}

// ---------------------------------------------------------------------------
// Combine: 64 blocks. cb<32: d1 rows (b=cb>>2, slice=cb&3; min over 8 octant
// planes). cb>=32: d2 cols (min over 16 rowgroup planes). Clamp >=0, fixed-
// order sum -> pb[cb] + token flag. Block 0 spins on all 64 flags (round-9-
// proven) and finalizes out[0]. Bit-identical every replay -> deterministic.
// ---------------------------------------------------------------------------
__global__ __launch_bounds__(BLK) void combine_kernel(
        const float* __restrict__ rpart, const float* __restrict__ cpart,
        float* __restrict__ pb, unsigned* __restrict__ flags,
        float* __restrict__ out) {
    __shared__ float ws4[4];
    __shared__ float sh[64];
    int cb = blockIdx.x;               // 0..63
    float s = 0.0f;
    if (cb < 32) {
        int b = cb >> 2, slice = cb & 3;
        const float* p = rpart + ((size_t)(b * NOCT) << 12);
        #pragma unroll
        for (int k = 0; k < 4; ++k) {
            int row = slice * 1024 + k * BLK + threadIdx.x;
            float m = p[row];
            #pragma unroll
            for (int o = 1; o < NOCT; ++o)
                m = fminf(m, p[((size_t)o << 12) + row]);
            s += fmaxf(m, 0.0f);
        }
    } else {
        int b = (cb - 32) >> 2, slice = (cb - 32) & 3;
        const float* p = cpart + ((size_t)(b * NRG) << 12);
        #pragma unroll
        for (int k = 0; k < 4; ++k) {
            int colx = slice * 1024 + k * BLK + threadIdx.x;
            float m = p[colx];
            #pragma unroll
            for (int g = 1; g < NRG; ++g)
                m = fminf(m, p[((size_t)g << 12) + colx]);
            s += fmaxf(m, 0.0f);
        }
    }
    for (int off = 32; off > 0; off >>= 1) s += __shfl_down(s, off);
    int wid = threadIdx.x >> 6, lane = threadIdx.x & 63;
    if (lane == 0) ws4[wid] = s;
    __syncthreads();
    if (threadIdx.x == 0) {
        float t = ws4[0] + ws4[1] + ws4[2] + ws4[3];
        atomicExch((unsigned*)(pb + cb), __float_as_uint(t));
        __threadfence();
        atomicExch(flags + cb, flag_token(cb));
    }

    if (cb == 0) {
        __syncthreads();
        int t = threadIdx.x;
        if (t < 64) {
            unsigned want = flag_token(t);
            while (atomicAdd(flags + t, 0u) != want) {
                __builtin_amdgcn_s_sleep(1);
            }
            sh[t] = __uint_as_float(atomicAdd((unsigned*)(pb + t), 0u));
        }
        __syncthreads();
        if (t == 0) {
            float acc = 0.0f;
            #pragma unroll
            for (int bb = 0; bb < BATCH; ++bb) {
                float d1 = sh[bb * 4] + sh[bb * 4 + 1] + sh[bb * 4 + 2] + sh[bb * 4 + 3];
                float d2 = sh[32 + bb * 4] + sh[32 + bb * 4 + 1] +
                           sh[32 + bb * 4 + 2] + sh[32 + bb * 4 + 3];
                acc += fmaxf(d1, d2);
            }
            out[0] = acc * (1.0f / (float)NPTS) * (1.0f / (float)BATCH);
        }
    }
}

extern "C" void kernel_launch(void* const* d_in, const int* in_sizes, int n_in,
                              void* d_out, int out_size, void* d_ws, size_t ws_size,
                              hipStream_t stream) {
    const float* ori = (const float*)d_in[0];
    const float* adv = (const float*)d_in[1];
    float* out = (float*)d_out;

    // ws: rpart[8][8][4096] (1 MB) | cpart[8][16][4096] (2 MB) | pb[64] | flags[64]
    float* rpart = (float*)d_ws;
    float* cpart = rpart + (size_t)BATCH * NOCT * NPTS;
    float* pb = cpart + (size_t)BATCH * NRG * NPTS;
    unsigned* flags = (unsigned*)(pb + 64);

    chamfer_sym<<<BATCH * NRG * NOCT, BLK, 0, stream>>>(ori, adv, rpart, cpart);
    combine_kernel<<<64, BLK, 0, stream>>>(rpart, cpart, pb, flags, out);
}

// Round 14
// 22.657 us; speedup vs baseline: 1.4719x; 1.4719x over previous
//
#include <hip/hip_runtime.h>
#include <float.h>

#define BATCH 8
#define NPTS 4096
#define BLK 512               // 8 waves
#define THALF 1024            // targets per block (one quarter)
#define NH 4                  // target quarters

typedef __attribute__((ext_vector_type(8))) short short8;      // 8 bf16
typedef __attribute__((ext_vector_type(16))) float floatx16;   // 32x32 MFMA acc

union U4S8 { uint4 u; short8 s; };

// round-to-nearest-even f32 -> bf16 bits
__device__ inline unsigned short f2bf(float f) {
    unsigned u = __float_as_uint(f);
    return (unsigned short)((u + 0x7FFFu + ((u >> 16) & 1u)) >> 16);
}
__device__ inline float bf2f(unsigned short h) {
    return __uint_as_float(((unsigned)h) << 16);
}
__device__ inline unsigned flag_token(int i) {
    return 0x9E3779B9u * (unsigned)(i + 7);   // never 0xAAAAAAAA poison
}

// ---------------------------------------------------------------------------
// Main kernel: grid = 1024 = (dirb(16), rowgroup(16), quarter(4)).
// CHANGE vs round 10 (best, 23.3us): 8 waves x ONE 32-row band each (512
// threads) instead of 4 waves x 2 bands. Same block coverage (256 rows x
// 1024 targets), same 4 waves/SIMD occupancy (2 blocks/CU, 16 KB LDS,
// __launch_bounds__(512,4) -> VGPR cap 128), but halved in-flight
// accumulator state: live regs ~92 << 128 -> provably spill-free, where
// round 10's 2-band version sat at ~130 (right at the spill boundary).
// Numerics identical to rounds 7-13 (absmax 0.0): K=16 hi/lo bf16 encoding
// folds |q|^2 + |t|^2 - 2q.t into one mfma_f32_32x32x16_bf16.
// ---------------------------------------------------------------------------
__global__ __launch_bounds__(BLK, 4) void chamfer_partial(
        const float* __restrict__ ori, const float* __restrict__ adv,
        float* __restrict__ rfin) {
    __shared__ uint4 sm[THALF];   // 16 KB

    int bx = blockIdx.x;               // 0..1023
    int half = bx & (NH - 1);
    int rowgroup = (bx >> 2) & 15;
    int dirb = bx >> 6;                // 0..15
    int b = dirb & 7;
    int dir = dirb >> 3;

    const float* qsrc = dir ? adv : ori;   // dir0: ori->adv, dir1: adv->ori
    const float* tsrc = dir ? ori : adv;

    // ---- stage this quarter's 1024 targets, packed hi/lo, into LDS ----
    {
        const float* tx = tsrc + (b * 3 + 0) * NPTS;
        const float* ty = tsrc + (b * 3 + 1) * NPTS;
        const float* tz = tsrc + (b * 3 + 2) * NPTS;
        #pragma unroll
        for (int i = 0; i < THALF / BLK; ++i) {
            int p = threadIdx.x + i * BLK;
            int m = half * THALF + p;
            float x = tx[m], y = ty[m], z = tz[m];
            float n2 = fmaf(x, x, fmaf(y, y, z * z));
            unsigned short hx = f2bf(x), hy = f2bf(y), hz = f2bf(z);
            unsigned short lx = f2bf(x - bf2f(hx));
            unsigned short ly = f2bf(y - bf2f(hy));
            unsigned short lz = f2bf(z - bf2f(hz));
            unsigned short h2 = f2bf(n2);
            unsigned short l2 = f2bf(n2 - bf2f(h2));
            uint4 u;
            u.x = (unsigned)hx | ((unsigned)hy << 16);
            u.y = (unsigned)hz | ((unsigned)lx << 16);
            u.z = (unsigned)ly | ((unsigned)lz << 16);
            u.w = (unsigned)h2 | ((unsigned)l2 << 16);
            sm[p] = u;
        }
    }

    // ---- per-wave A fragment: ONE band of 32 rows ----
    int w = threadIdx.x >> 6;          // wave 0..7
    int l = threadIdx.x & 63;
    int lrow = l & 31;
    int kh = l >> 5;

    short8 afrag;
    {
        int q = rowgroup * 256 + w * 32 + lrow;
        float x = qsrc[(b * 3 + 0) * NPTS + q];
        float y = qsrc[(b * 3 + 1) * NPTS + q];
        float z = qsrc[(b * 3 + 2) * NPTS + q];
        float n2 = fmaf(x, x, fmaf(y, y, z * z));
        unsigned short hx = f2bf(x), hy = f2bf(y), hz = f2bf(z);
        unsigned short lx = f2bf(x - bf2f(hx));
        unsigned short ly = f2bf(y - bf2f(hy));
        unsigned short lz = f2bf(z - bf2f(hz));
        unsigned short h2 = f2bf(n2);
        unsigned short l2 = f2bf(n2 - bf2f(h2));
        unsigned short mhx = f2bf(-2.0f * bf2f(hx));
        unsigned short mhy = f2bf(-2.0f * bf2f(hy));
        unsigned short mhz = f2bf(-2.0f * bf2f(hz));
        unsigned short mlx = f2bf(-2.0f * bf2f(lx));
        unsigned short mly = f2bf(-2.0f * bf2f(ly));
        unsigned short mlz = f2bf(-2.0f * bf2f(lz));
        const unsigned short one = 0x3F80;
        union { unsigned short us[8]; short8 s8; } A;
        if (kh == 0) {
            A.us[0] = mhx; A.us[1] = mhy; A.us[2] = mhz;
            A.us[3] = mhx; A.us[4] = mhy; A.us[5] = mhz;
            A.us[6] = one; A.us[7] = one;
        } else {
            A.us[0] = mlx; A.us[1] = mly; A.us[2] = mlz;
            A.us[3] = h2;  A.us[4] = l2;
            A.us[5] = 0;   A.us[6] = 0;   A.us[7] = 0;
        }
        afrag = A.s8;
    }
    __syncthreads();

    floatx16 zero, rmn;
    #pragma unroll
    for (int r = 0; r < 16; ++r) { zero[r] = 0.0f; rmn[r] = FLT_MAX; }

    bool hi = (kh == 1);
    int col = lrow;

#define PROCESS2(r0, r1)                                                       \
    {                                                                          \
        U4S8 f0, f1;                                                           \
        f0.u.x = (r0).x;                                                       \
        f0.u.y = hi ? (((r0).y & 0xFFFFu) | 0x3F800000u) : (r0).y;             \
        f0.u.z = hi ? 0x00003F80u : (r0).z;                                    \
        f0.u.w = hi ? 0u : (r0).w;                                             \
        f1.u.x = (r1).x;                                                       \
        f1.u.y = hi ? (((r1).y & 0xFFFFu) | 0x3F800000u) : (r1).y;             \
        f1.u.z = hi ? 0x00003F80u : (r1).z;                                    \
        f1.u.w = hi ? 0u : (r1).w;                                             \
        floatx16 a0 = __builtin_amdgcn_mfma_f32_32x32x16_bf16(afrag, f0.s, zero, 0, 0, 0); \
        floatx16 a1 = __builtin_amdgcn_mfma_f32_32x32x16_bf16(afrag, f1.s, zero, 0, 0, 0); \
        _Pragma("unroll")                                                      \
        for (int r = 0; r < 16; ++r)                                           \
            rmn[r] = fminf(fminf(rmn[r], a0[r]), a1[r]);   /* -> v_min3 */     \
    }

    // ping-pong pipelined loop over this quarter's 32 col-tiles (2 per iter)
    {
        uint4 r0 = sm[col], r1 = sm[32 + col];
        #pragma unroll 1
        for (int ct = 0; ct < 30; ct += 2) {
            uint4 p0 = sm[(ct + 2) * 32 + col];
            uint4 p1 = sm[(ct + 3) * 32 + col];
            PROCESS2(r0, r1);
            r0 = p0; r1 = p1;
        }
        PROCESS2(r0, r1);
    }
#undef PROCESS2

    // ---- butterfly row-min over the 32 cols; write partial row-mins ----
    #pragma unroll
    for (int r = 0; r < 16; ++r) {
        float v = rmn[r];
        #pragma unroll
        for (int m = 1; m <= 16; m <<= 1)
            v = fminf(v, __shfl_xor(v, m));
        rmn[r] = v;
    }
    if (lrow == 0) {
        // C/D row = (r&3) + 8*(r>>2) + 4*kh (verified m74/m101, rounds 7-13)
        float* d = rfin + (((size_t)(dirb * NH + half)) << 12)
                 + rowgroup * 256 + w * 32 + kh * 4;
        #pragma unroll
        for (int r = 0; r < 16; ++r)
            d[(r & 3) + 8 * (r >> 2)] = rmn[r];
    }
}

// ---------------------------------------------------------------------------
// Combine: byte-identical to round 10's proven version. 16 blocks (one per
// dirb): min over 4 quarter-partials, clamp, fixed-order sum -> bsum[dirb]
// + token flag; block 0 spins on the 16 flags and finalizes out[0].
// Bit-identical values every replay -> deterministic.
// ---------------------------------------------------------------------------
__global__ __launch_bounds__(256) void combine_kernel(
        const float* __restrict__ rfin, float* __restrict__ bsum,
        unsigned* __restrict__ flags, float* __restrict__ out) {
    __shared__ float ws[4];
    __shared__ float sh[16];
    int dirb = blockIdx.x;
    const float* p = rfin + (((size_t)dirb * NH) << 12);
    float s = 0.0f;
    #pragma unroll
    for (int k = 0; k < 16; ++k) {
        int row = k * 256 + threadIdx.x;
        float m = fminf(fminf(p[row], p[(1 << 12) + row]),
                        fminf(p[(2 << 12) + row], p[(3 << 12) + row]));
        s += fmaxf(m, 0.0f);
    }
    for (int off = 32; off > 0; off >>= 1) s += __shfl_down(s, off);
    int wid = threadIdx.x >> 6, lane = threadIdx.x & 63;
    if (lane == 0) ws[wid] = s;
    __syncthreads();
    if (threadIdx.x == 0) {
        float t = ws[0] + ws[1] + ws[2] + ws[3];
        atomicExch((unsigned*)(bsum + dirb), __float_as_uint(t));
        __threadfence();
        atomicExch(flags + dirb, flag_token(dirb));
    }

    if (dirb == 0) {
        __syncthreads();
        int t = threadIdx.x;
        if (t < 16) {
            unsigned want = flag_token(t);
            while (atomicAdd(flags + t, 0u) != want) {
                __builtin_amdgcn_s_sleep(1);
            }
            sh[t] = __uint_as_float(atomicAdd((unsigned*)(bsum + t), 0u));
        }
        __syncthreads();
        if (t == 0) {
            float acc = 0.0f;
            #pragma unroll
            for (int bb = 0; bb < BATCH; ++bb)
                acc += fmaxf(sh[bb], sh[8 + bb]);
            out[0] = acc * (1.0f / (float)NPTS) * (1.0f / (float)BATCH);
        }
    }
}

extern "C" void kernel_launch(void* const* d_in, const int* in_sizes, int n_in,
                              void* d_out, int out_size, void* d_ws, size_t ws_size,
                              hipStream_t stream) {
    const float* ori = (const float*)d_in[0];
    const float* adv = (const float*)d_in[1];
    float* out = (float*)d_out;

    // ws: rfin[16 dirb][4 quarter][4096 row] floats (1 MB) | bsum[16] | flags[16]
    float* rfin = (float*)d_ws;
    float* bsum = rfin + (size_t)16 * NH * NPTS;
    unsigned* flags = (unsigned*)(bsum + 16);

    chamfer_partial<<<16 * 16 * NH, BLK, 0, stream>>>(ori, adv, rfin);
    combine_kernel<<<16, 256, 0, stream>>>(rfin, bsum, flags, out);
}

// Round 15
// 19.713 us; speedup vs baseline: 1.6917x; 1.1493x over previous
//
#include <hip/hip_runtime.h>
#include <float.h>

#define BATCH 8
#define NPTS 4096
#define BLK 512               // 8 waves
#define THALF 1024            // targets per block (one quarter)
#define NH 4                  // target quarters
#define NRG 8                 // rowgroups of 512 rows

typedef __attribute__((ext_vector_type(8))) short short8;      // 8 bf16
typedef __attribute__((ext_vector_type(16))) float floatx16;   // 32x32 MFMA acc

union U4S8 { uint4 u; short8 s; };

// round-to-nearest-even f32 -> bf16 bits
__device__ inline unsigned short f2bf(float f) {
    unsigned u = __float_as_uint(f);
    return (unsigned short)((u + 0x7FFFu + ((u >> 16) & 1u)) >> 16);
}
__device__ inline float bf2f(unsigned short h) {
    return __uint_as_float(((unsigned)h) << 16);
}
__device__ inline unsigned flag_token(int i) {
    return 0x9E3779B9u * (unsigned)(i + 7);   // never 0xAAAAAAAA poison
}

// ---------------------------------------------------------------------------
// Main kernel: grid = 512 = (dirb(16), rowgroup(8), quarter(4)); 512 threads
// = 8 waves x 2 bands of 32 rows = 512 rows/block; 1024 targets (quarter) in
// LDS. ONE residency generation: 2 blocks/CU, 4 waves/SIMD
// (__launch_bounds__(512,4), VGPR cap 128, est live ~118).
// vs R14 (22.7us best): (1) each B-frag ds_read_b128 now feeds 2 MFMAs
// (bands sequenced so only one band's accs in flight) -> LDS reads halved;
// (2) epilogue = register-folding butterfly: 17 swizzles/band vs 80 (shfl ==
// ds_swizzle == LDS pipe), final mins distributed across 16 lanes (row =
// bitrev4(lane)) -> coalesced 1-float store per lane.
// Numerics identical to rounds 7-14 (absmax 0.0): K=16 hi/lo bf16 encoding
// folds |q|^2 + |t|^2 - 2q.t into one mfma_f32_32x32x16_bf16;
// C/D row = (r&3) + 8*(r>>2) + 4*kh (verified m74/m101).
// ---------------------------------------------------------------------------
__global__ __launch_bounds__(BLK, 4) void chamfer_partial(
        const float* __restrict__ ori, const float* __restrict__ adv,
        float* __restrict__ rfin) {
    __shared__ uint4 sm[THALF];   // 16 KB

    int bx = blockIdx.x;               // 0..511
    int half = bx & (NH - 1);
    int rowgroup = (bx >> 2) & (NRG - 1);
    int dirb = bx >> 5;                // 0..15
    int b = dirb & 7;
    int dir = dirb >> 3;

    const float* qsrc = dir ? adv : ori;   // dir0: ori->adv, dir1: adv->ori
    const float* tsrc = dir ? ori : adv;

    // ---- stage this quarter's 1024 targets, packed hi/lo, into LDS ----
    {
        const float* tx = tsrc + (b * 3 + 0) * NPTS;
        const float* ty = tsrc + (b * 3 + 1) * NPTS;
        const float* tz = tsrc + (b * 3 + 2) * NPTS;
        #pragma unroll
        for (int i = 0; i < THALF / BLK; ++i) {
            int p = threadIdx.x + i * BLK;
            int m = half * THALF + p;
            float x = tx[m], y = ty[m], z = tz[m];
            float n2 = fmaf(x, x, fmaf(y, y, z * z));
            unsigned short hx = f2bf(x), hy = f2bf(y), hz = f2bf(z);
            unsigned short lx = f2bf(x - bf2f(hx));
            unsigned short ly = f2bf(y - bf2f(hy));
            unsigned short lz = f2bf(z - bf2f(hz));
            unsigned short h2 = f2bf(n2);
            unsigned short l2 = f2bf(n2 - bf2f(h2));
            uint4 u;
            u.x = (unsigned)hx | ((unsigned)hy << 16);
            u.y = (unsigned)hz | ((unsigned)lx << 16);
            u.z = (unsigned)ly | ((unsigned)lz << 16);
            u.w = (unsigned)h2 | ((unsigned)l2 << 16);
            sm[p] = u;
        }
    }

    // ---- per-wave A fragments: 2 bands of 32 rows ----
    int w = threadIdx.x >> 6;          // wave 0..7
    int l = threadIdx.x & 63;
    int lrow = l & 31;
    int kh = l >> 5;

    short8 afrag0, afrag1;
    #pragma unroll
    for (int bi = 0; bi < 2; ++bi) {
        int q = rowgroup * 512 + (w * 2 + bi) * 32 + lrow;
        float x = qsrc[(b * 3 + 0) * NPTS + q];
        float y = qsrc[(b * 3 + 1) * NPTS + q];
        float z = qsrc[(b * 3 + 2) * NPTS + q];
        float n2 = fmaf(x, x, fmaf(y, y, z * z));
        unsigned short hx = f2bf(x), hy = f2bf(y), hz = f2bf(z);
        unsigned short lx = f2bf(x - bf2f(hx));
        unsigned short ly = f2bf(y - bf2f(hy));
        unsigned short lz = f2bf(z - bf2f(hz));
        unsigned short h2 = f2bf(n2);
        unsigned short l2 = f2bf(n2 - bf2f(h2));
        unsigned short mhx = f2bf(-2.0f * bf2f(hx));
        unsigned short mhy = f2bf(-2.0f * bf2f(hy));
        unsigned short mhz = f2bf(-2.0f * bf2f(hz));
        unsigned short mlx = f2bf(-2.0f * bf2f(lx));
        unsigned short mly = f2bf(-2.0f * bf2f(ly));
        unsigned short mlz = f2bf(-2.0f * bf2f(lz));
        const unsigned short one = 0x3F80;
        union { unsigned short us[8]; short8 s8; } A;
        if (kh == 0) {
            A.us[0] = mhx; A.us[1] = mhy; A.us[2] = mhz;
            A.us[3] = mhx; A.us[4] = mhy; A.us[5] = mhz;
            A.us[6] = one; A.us[7] = one;
        } else {
            A.us[0] = mlx; A.us[1] = mly; A.us[2] = mlz;
            A.us[3] = h2;  A.us[4] = l2;
            A.us[5] = 0;   A.us[6] = 0;   A.us[7] = 0;
        }
        if (bi == 0) afrag0 = A.s8; else afrag1 = A.s8;
    }
    __syncthreads();

    floatx16 zero, rmn0, rmn1;
    #pragma unroll
    for (int r = 0; r < 16; ++r) { zero[r] = 0.0f; rmn0[r] = FLT_MAX; rmn1[r] = FLT_MAX; }

    bool hi = (kh == 1);
    int col = lrow;

    // ---- main loop: 2 tiles/iter; each B-frag feeds BOTH bands; bands
    //      sequenced so only one band's accs are in flight ----
    {
        uint4 r0 = sm[col], r1 = sm[32 + col];
        #pragma unroll 1
        for (int ct = 0; ct < 32; ct += 2) {
            U4S8 f0, f1;
            f0.u.x = r0.x;
            f0.u.y = hi ? ((r0.y & 0xFFFFu) | 0x3F800000u) : r0.y;
            f0.u.z = hi ? 0x00003F80u : r0.z;
            f0.u.w = hi ? 0u : r0.w;
            f1.u.x = r1.x;
            f1.u.y = hi ? ((r1.y & 0xFFFFu) | 0x3F800000u) : r1.y;
            f1.u.z = hi ? 0x00003F80u : r1.z;
            f1.u.w = hi ? 0u : r1.w;
            // prefetch next tile pair (wraps harmlessly at the end)
            int nt = (ct + 2) & 31;
            r0 = sm[(nt << 5) + col];
            r1 = sm[((nt + 1) << 5) + col];
            // band 0
            {
                floatx16 a0 = __builtin_amdgcn_mfma_f32_32x32x16_bf16(afrag0, f0.s, zero, 0, 0, 0);
                floatx16 a1 = __builtin_amdgcn_mfma_f32_32x32x16_bf16(afrag0, f1.s, zero, 0, 0, 0);
                #pragma unroll
                for (int r = 0; r < 16; ++r)
                    rmn0[r] = fminf(fminf(rmn0[r], a0[r]), a1[r]);   // v_min3
            }
            // band 1
            {
                floatx16 c0 = __builtin_amdgcn_mfma_f32_32x32x16_bf16(afrag1, f0.s, zero, 0, 0, 0);
                floatx16 c1 = __builtin_amdgcn_mfma_f32_32x32x16_bf16(afrag1, f1.s, zero, 0, 0, 0);
                #pragma unroll
                for (int r = 0; r < 16; ++r)
                    rmn1[r] = fminf(fminf(rmn1[r], c0[r]), c1[r]);
            }
        }
    }

    // ---- epilogue: register-folding butterfly (17 swizzles/band vs 80) ----
    bool b0 = (l & 1), b1 = (l & 2), b2 = (l & 4), b3 = (l & 8);

#define FOLD(v)                                                                \
    {                                                                          \
        _Pragma("unroll")                                                      \
        for (int i = 0; i < 8; ++i) {                                          \
            float send = b0 ? v[i] : v[i + 8];                                 \
            float recv = __shfl_xor(send, 1);                                  \
            v[i] = fminf(b0 ? v[i + 8] : v[i], recv);                          \
        }                                                                      \
        _Pragma("unroll")                                                      \
        for (int i = 0; i < 4; ++i) {                                          \
            float send = b1 ? v[i] : v[i + 4];                                 \
            float recv = __shfl_xor(send, 2);                                  \
            v[i] = fminf(b1 ? v[i + 4] : v[i], recv);                          \
        }                                                                      \
        _Pragma("unroll")                                                      \
        for (int i = 0; i < 2; ++i) {                                          \
            float send = b2 ? v[i] : v[i + 2];                                 \
            float recv = __shfl_xor(send, 4);                                  \
            v[i] = fminf(b2 ? v[i + 2] : v[i], recv);                          \
        }                                                                      \
        {                                                                      \
            float send = b3 ? v[0] : v[1];                                     \
            float recv = __shfl_xor(send, 8);                                  \
            v[0] = fminf(b3 ? v[1] : v[0], recv);                              \
        }                                                                      \
        v[0] = fminf(v[0], __shfl_xor(v[0], 16));                              \
    }

    FOLD(rmn0);
    FOLD(rmn1);
#undef FOLD

    // after folding: lane g = l&15 holds reg rr = bitrev4(g); its row within
    // the band = (rr&3) + 8*(rr>>2) + 4*kh. Lanes with (l&16)==0 store.
    if ((l & 16) == 0) {
        int g = l & 15;
        int rr = ((g & 1) << 3) | ((g & 2) << 1) | ((g & 4) >> 1) | ((g & 8) >> 3);
        int rowin = (rr & 3) + 8 * (rr >> 2) + 4 * kh;
        float* base = rfin + (((size_t)(dirb * NH + half)) << 12)
                    + rowgroup * 512;
        base[(w * 2 + 0) * 32 + rowin] = rmn0[0];
        base[(w * 2 + 1) * 32 + rowin] = rmn1[0];
    }
}

// ---------------------------------------------------------------------------
// Combine: byte-identical to round 10/14's proven version. 16 blocks (one
// per dirb): min over 4 quarter-partials, clamp, fixed-order sum ->
// bsum[dirb] + token flag; block 0 spins on the 16 flags and finalizes
// out[0]. Bit-identical values every replay -> deterministic.
// ---------------------------------------------------------------------------
__global__ __launch_bounds__(256) void combine_kernel(
        const float* __restrict__ rfin, float* __restrict__ bsum,
        unsigned* __restrict__ flags, float* __restrict__ out) {
    __shared__ float ws[4];
    __shared__ float sh[16];
    int dirb = blockIdx.x;
    const float* p = rfin + (((size_t)dirb * NH) << 12);
    float s = 0.0f;
    #pragma unroll
    for (int k = 0; k < 16; ++k) {
        int row = k * 256 + threadIdx.x;
        float m = fminf(fminf(p[row], p[(1 << 12) + row]),
                        fminf(p[(2 << 12) + row], p[(3 << 12) + row]));
        s += fmaxf(m, 0.0f);
    }
    for (int off = 32; off > 0; off >>= 1) s += __shfl_down(s, off);
    int wid = threadIdx.x >> 6, lane = threadIdx.x & 63;
    if (lane == 0) ws[wid] = s;
    __syncthreads();
    if (threadIdx.x == 0) {
        float t = ws[0] + ws[1] + ws[2] + ws[3];
        atomicExch((unsigned*)(bsum + dirb), __float_as_uint(t));
        __threadfence();
        atomicExch(flags + dirb, flag_token(dirb));
    }

    if (dirb == 0) {
        __syncthreads();
        int t = threadIdx.x;
        if (t < 16) {
            unsigned want = flag_token(t);
            while (atomicAdd(flags + t, 0u) != want) {
                __builtin_amdgcn_s_sleep(1);
            }
            sh[t] = __uint_as_float(atomicAdd((unsigned*)(bsum + t), 0u));
        }
        __syncthreads();
        if (t == 0) {
            float acc = 0.0f;
            #pragma unroll
            for (int bb = 0; bb < BATCH; ++bb)
                acc += fmaxf(sh[bb], sh[8 + bb]);
            out[0] = acc * (1.0f / (float)NPTS) * (1.0f / (float)BATCH);
        }
    }
}

extern "C" void kernel_launch(void* const* d_in, const int* in_sizes, int n_in,
                              void* d_out, int out_size, void* d_ws, size_t ws_size,
                              hipStream_t stream) {
    const float* ori = (const float*)d_in[0];
    const float* adv = (const float*)d_in[1];
    float* out = (float*)d_out;

    // ws: rfin[16 dirb][4 quarter][4096 row] floats (1 MB) | bsum[16] | flags[16]
    float* rfin = (float*)d_ws;
    float* bsum = rfin + (size_t)16 * NH * NPTS;
    unsigned* flags = (unsigned*)(bsum + 16);

    chamfer_partial<<<16 * NRG * NH, BLK, 0, stream>>>(ori, adv, rfin);
    combine_kernel<<<16, 256, 0, stream>>>(rfin, bsum, flags, out);
}

// Round 16
// 19.230 us; speedup vs baseline: 1.7342x; 1.0251x over previous
//
#include <hip/hip_runtime.h>
#include <float.h>

#define BATCH 8
#define NPTS 4096
#define BLK 512               // 8 waves
#define THALF 1024            // targets per block (one quarter)
#define NH 4                  // target quarters
#define NRG 8                 // rowgroups of 512 rows

typedef __attribute__((ext_vector_type(8))) short short8;      // 8 bf16
typedef __attribute__((ext_vector_type(16))) float floatx16;   // 32x32 MFMA acc

union U4S8 { uint4 u; short8 s; };

// round-to-nearest-even f32 -> bf16 bits
__device__ inline unsigned short f2bf(float f) {
    unsigned u = __float_as_uint(f);
    return (unsigned short)((u + 0x7FFFu + ((u >> 16) & 1u)) >> 16);
}
__device__ inline float bf2f(unsigned short h) {
    return __uint_as_float(((unsigned)h) << 16);
}
__device__ inline unsigned flag_token(int i) {
    return 0x9E3779B9u * (unsigned)(i + 7);   // never 0xAAAAAAAA poison
}

// ---------------------------------------------------------------------------
// Main kernel: grid = 512 = (dirb(16), rowgroup(8), quarter(4)); 512 threads
// = 8 waves x 2 bands of 32 rows = 512 rows/block; 1024 targets (quarter) in
// LDS. ONE residency generation: 2 blocks/CU, 4 waves/SIMD
// (__launch_bounds__(512,4), VGPR cap 128, est live ~118).
// vs R14 (22.7us best): (1) each B-frag ds_read_b128 now feeds 2 MFMAs
// (bands sequenced so only one band's accs in flight) -> LDS reads halved;
// (2) epilogue = register-folding butterfly: 17 swizzles/band vs 80 (shfl ==
// ds_swizzle == LDS pipe), final mins distributed across 16 lanes (row =
// bitrev4(lane)) -> coalesced 1-float store per lane.
// Numerics identical to rounds 7-14 (absmax 0.0): K=16 hi/lo bf16 encoding
// folds |q|^2 + |t|^2 - 2q.t into one mfma_f32_32x32x16_bf16;
// C/D row = (r&3) + 8*(r>>2) + 4*kh (verified m74/m101).
// ---------------------------------------------------------------------------
__global__ __launch_bounds__(BLK, 4) void chamfer_partial(
        const float* __restrict__ ori, const float* __restrict__ adv,
        float* __restrict__ rfin) {
    __shared__ uint4 sm[THALF];   // 16 KB

    int bx = blockIdx.x;               // 0..511
    int half = bx & (NH - 1);
    int rowgroup = (bx >> 2) & (NRG - 1);
    int dirb = bx >> 5;                // 0..15
    int b = dirb & 7;
    int dir = dirb >> 3;

    const float* qsrc = dir ? adv : ori;   // dir0: ori->adv, dir1: adv->ori
    const float* tsrc = dir ? ori : adv;

    // ---- stage this quarter's 1024 targets, packed hi/lo, into LDS ----
    {
        const float* tx = tsrc + (b * 3 + 0) * NPTS;
        const float* ty = tsrc + (b * 3 + 1) * NPTS;
        const float* tz = tsrc + (b * 3 + 2) * NPTS;
        #pragma unroll
        for (int i = 0; i < THALF / BLK; ++i) {
            int p = threadIdx.x + i * BLK;
            int m = half * THALF + p;
            float x = tx[m], y = ty[m], z = tz[m];
            float n2 = fmaf(x, x, fmaf(y, y, z * z));
            unsigned short hx = f2bf(x), hy = f2bf(y), hz = f2bf(z);
            unsigned short lx = f2bf(x - bf2f(hx));
            unsigned short ly = f2bf(y - bf2f(hy));
            unsigned short lz = f2bf(z - bf2f(hz));
            unsigned short h2 = f2bf(n2);
            unsigned short l2 = f2bf(n2 - bf2f(h2));
            uint4 u;
            u.x = (unsigned)hx | ((unsigned)hy << 16);
            u.y = (unsigned)hz | ((unsigned)lx << 16);
            u.z = (unsigned)ly | ((unsigned)lz << 16);
            u.w = (unsigned)h2 | ((unsigned)l2 << 16);
            sm[p] = u;
        }
    }

    // ---- per-wave A fragments: 2 bands of 32 rows ----
    int w = threadIdx.x >> 6;          // wave 0..7
    int l = threadIdx.x & 63;
    int lrow = l & 31;
    int kh = l >> 5;

    short8 afrag0, afrag1;
    #pragma unroll
    for (int bi = 0; bi < 2; ++bi) {
        int q = rowgroup * 512 + (w * 2 + bi) * 32 + lrow;
        float x = qsrc[(b * 3 + 0) * NPTS + q];
        float y = qsrc[(b * 3 + 1) * NPTS + q];
        float z = qsrc[(b * 3 + 2) * NPTS + q];
        float n2 = fmaf(x, x, fmaf(y, y, z * z));
        unsigned short hx = f2bf(x), hy = f2bf(y), hz = f2bf(z);
        unsigned short lx = f2bf(x - bf2f(hx));
        unsigned short ly = f2bf(y - bf2f(hy));
        unsigned short lz = f2bf(z - bf2f(hz));
        unsigned short h2 = f2bf(n2);
        unsigned short l2 = f2bf(n2 - bf2f(h2));
        unsigned short mhx = f2bf(-2.0f * bf2f(hx));
        unsigned short mhy = f2bf(-2.0f * bf2f(hy));
        unsigned short mhz = f2bf(-2.0f * bf2f(hz));
        unsigned short mlx = f2bf(-2.0f * bf2f(lx));
        unsigned short mly = f2bf(-2.0f * bf2f(ly));
        unsigned short mlz = f2bf(-2.0f * bf2f(lz));
        const unsigned short one = 0x3F80;
        union { unsigned short us[8]; short8 s8; } A;
        if (kh == 0) {
            A.us[0] = mhx; A.us[1] = mhy; A.us[2] = mhz;
            A.us[3] = mhx; A.us[4] = mhy; A.us[5] = mhz;
            A.us[6] = one; A.us[7] = one;
        } else {
            A.us[0] = mlx; A.us[1] = mly; A.us[2] = mlz;
            A.us[3] = h2;  A.us[4] = l2;
            A.us[5] = 0;   A.us[6] = 0;   A.us[7] = 0;
        }
        if (bi == 0) afrag0 = A.s8; else afrag1 = A.s8;
    }
    __syncthreads();

    floatx16 zero, rmn0, rmn1;
    #pragma unroll
    for (int r = 0; r < 16; ++r) { zero[r] = 0.0f; rmn0[r] = FLT_MAX; rmn1[r] = FLT_MAX; }

    bool hi = (kh == 1);
    int col = lrow;

    // ---- main loop: 2 tiles/iter; each B-frag feeds BOTH bands; bands
    //      sequenced so only one band's accs are in flight ----
    {
        uint4 r0 = sm[col], r1 = sm[32 + col];
        #pragma unroll 1
        for (int ct = 0; ct < 32; ct += 2) {
            U4S8 f0, f1;
            f0.u.x = r0.x;
            f0.u.y = hi ? ((r0.y & 0xFFFFu) | 0x3F800000u) : r0.y;
            f0.u.z = hi ? 0x00003F80u : r0.z;
            f0.u.w = hi ? 0u : r0.w;
            f1.u.x = r1.x;
            f1.u.y = hi ? ((r1.y & 0xFFFFu) | 0x3F800000u) : r1.y;
            f1.u.z = hi ? 0x00003F80u : r1.z;
            f1.u.w = hi ? 0u : r1.w;
            // prefetch next tile pair (wraps harmlessly at the end)
            int nt = (ct + 2) & 31;
            r0 = sm[(nt << 5) + col];
            r1 = sm[((nt + 1) << 5) + col];
            // band 0
            {
                floatx16 a0 = __builtin_amdgcn_mfma_f32_32x32x16_bf16(afrag0, f0.s, zero, 0, 0, 0);
                floatx16 a1 = __builtin_amdgcn_mfma_f32_32x32x16_bf16(afrag0, f1.s, zero, 0, 0, 0);
                #pragma unroll
                for (int r = 0; r < 16; ++r)
                    rmn0[r] = fminf(fminf(rmn0[r], a0[r]), a1[r]);   // v_min3
            }
            // band 1
            {
                floatx16 c0 = __builtin_amdgcn_mfma_f32_32x32x16_bf16(afrag1, f0.s, zero, 0, 0, 0);
                floatx16 c1 = __builtin_amdgcn_mfma_f32_32x32x16_bf16(afrag1, f1.s, zero, 0, 0, 0);
                #pragma unroll
                for (int r = 0; r < 16; ++r)
                    rmn1[r] = fminf(fminf(rmn1[r], c0[r]), c1[r]);
            }
        }
    }

    // ---- epilogue: register-folding butterfly (17 swizzles/band vs 80) ----
    bool b0 = (l & 1), b1 = (l & 2), b2 = (l & 4), b3 = (l & 8);

#define FOLD(v)                                                                \
    {                                                                          \
        _Pragma("unroll")                                                      \
        for (int i = 0; i < 8; ++i) {                                          \
            float send = b0 ? v[i] : v[i + 8];                                 \
            float recv = __shfl_xor(send, 1);                                  \
            v[i] = fminf(b0 ? v[i + 8] : v[i], recv);                          \
        }                                                                      \
        _Pragma("unroll")                                                      \
        for (int i = 0; i < 4; ++i) {                                          \
            float send = b1 ? v[i] : v[i + 4];                                 \
            float recv = __shfl_xor(send, 2);                                  \
            v[i] = fminf(b1 ? v[i + 4] : v[i], recv);                          \
        }                                                                      \
        _Pragma("unroll")                                                      \
        for (int i = 0; i < 2; ++i) {                                          \
            float send = b2 ? v[i] : v[i + 2];                                 \
            float recv = __shfl_xor(send, 4);                                  \
            v[i] = fminf(b2 ? v[i + 2] : v[i], recv);                          \
        }                                                                      \
        {                                                                      \
            float send = b3 ? v[0] : v[1];                                     \
            float recv = __shfl_xor(send, 8);                                  \
            v[0] = fminf(b3 ? v[1] : v[0], recv);                              \
        }                                                                      \
        v[0] = fminf(v[0], __shfl_xor(v[0], 16));                              \
    }

    FOLD(rmn0);
    FOLD(rmn1);
#undef FOLD

    // after folding: lane g = l&15 holds reg rr = bitrev4(g); its row within
    // the band = (rr&3) + 8*(rr>>2) + 4*kh. Lanes with (l&16)==0 store.
    if ((l & 16) == 0) {
        int g = l & 15;
        int rr = ((g & 1) << 3) | ((g & 2) << 1) | ((g & 4) >> 1) | ((g & 8) >> 3);
        int rowin = (rr & 3) + 8 * (rr >> 2) + 4 * kh;
        float* base = rfin + (((size_t)(dirb * NH + half)) << 12)
                    + rowgroup * 512;
        base[(w * 2 + 0) * 32 + rowin] = rmn0[0];
        base[(w * 2 + 1) * 32 + rowin] = rmn1[0];
    }
}

// ---------------------------------------------------------------------------
// Combine: byte-identical to round 10/14's proven version. 16 blocks (one
// per dirb): min over 4 quarter-partials, clamp, fixed-order sum ->
// bsum[dirb] + token flag; block 0 spins on the 16 flags and finalizes
// out[0]. Bit-identical values every replay -> deterministic.
// ---------------------------------------------------------------------------
__global__ __launch_bounds__(256) void combine_kernel(
        const float* __restrict__ rfin, float* __restrict__ bsum,
        unsigned* __restrict__ flags, float* __restrict__ out) {
    __shared__ float ws[4];
    __shared__ float sh[16];
    int dirb = blockIdx.x;
    const float* p = rfin + (((size_t)dirb * NH) << 12);
    float s = 0.0f;
    #pragma unroll
    for (int k = 0; k < 16; ++k) {
        int row = k * 256 + threadIdx.x;
        float m = fminf(fminf(p[row], p[(1 << 12) + row]),
                        fminf(p[(2 << 12) + row], p[(3 << 12) + row]));
        s += fmaxf(m, 0.0f);
    }
    for (int off = 32; off > 0; off >>= 1) s += __shfl_down(s, off);
    int wid = threadIdx.x >> 6, lane = threadIdx.x & 63;
    if (lane == 0) ws[wid] = s;
    __syncthreads();
    if (threadIdx.x == 0) {
        float t = ws[0] + ws[1] + ws[2] + ws[3];
        atomicExch((unsigned*)(bsum + dirb), __float_as_uint(t));
        __threadfence();
        atomicExch(flags + dirb, flag_token(dirb));
    }

    if (dirb == 0) {
        __syncthreads();
        int t = threadIdx.x;
        if (t < 16) {
            unsigned want = flag_token(t);
            while (atomicAdd(flags + t, 0u) != want) {
                __builtin_amdgcn_s_sleep(1);
            }
            sh[t] = __uint_as_float(atomicAdd((unsigned*)(bsum + t), 0u));
        }
        __syncthreads();
        if (t == 0) {
            float acc = 0.0f;
            #pragma unroll
            for (int bb = 0; bb < BATCH; ++bb)
                acc += fmaxf(sh[bb], sh[8 + bb]);
            out[0] = acc * (1.0f / (float)NPTS) * (1.0f / (float)BATCH);
        }
    }
}

extern "C" void kernel_launch(void* const* d_in, const int* in_sizes, int n_in,
                              void* d_out, int out_size, void* d_ws, size_t ws_size,
                              hipStream_t stream) {
    const float* ori = (const float*)d_in[0];
    const float* adv = (const float*)d_in[1];
    float* out = (float*)d_out;

    // ws: rfin[16 dirb][4 quarter][4096 row] floats (1 MB) | bsum[16] | flags[16]
    float* rfin = (float*)d_ws;
    float* bsum = rfin + (size_t)16 * NH * NPTS;
    unsigned* flags = (unsigned*)(bsum + 16);

    chamfer_partial<<<16 * NRG * NH, BLK, 0, stream>>>(ori, adv, rfin);
    combine_kernel<<<16, 256, 0, stream>>>(rfin, bsum, flags, out);
}

// Round 17
// 19.001 us; speedup vs baseline: 1.7551x; 1.0121x over previous
//
#include <hip/hip_runtime.h>
#include <float.h>

#define BATCH 8
#define NPTS 4096
#define BLK 512               // 8 waves
#define THALF 1024            // targets per block (one quarter)
#define NH 4                  // target quarters
#define NRG 8                 // rowgroups of 512 rows

typedef __attribute__((ext_vector_type(8))) short short8;      // 8 bf16
typedef __attribute__((ext_vector_type(16))) float floatx16;   // 32x32 MFMA acc

union U4S8 { uint4 u; short8 s; };
__device__ inline short8 asS8(uint4 u) { U4S8 t; t.u = u; return t.s; }

// round-to-nearest-even f32 -> bf16 bits
__device__ inline unsigned short f2bf(float f) {
    unsigned u = __float_as_uint(f);
    return (unsigned short)((u + 0x7FFFu + ((u >> 16) & 1u)) >> 16);
}
__device__ inline float bf2f(unsigned short h) {
    return __uint_as_float(((unsigned)h) << 16);
}
__device__ inline unsigned flag_token(int i) {
    return 0x9E3779B9u * (unsigned)(i + 7);   // never 0xAAAAAAAA poison
}

// ---------------------------------------------------------------------------
// Main kernel: grid = 512 = (dirb(16), rowgroup(8), quarter(4)); 8 waves x
// 2 bands of 32 rows; 1024 targets in LDS. One residency generation
// (2 blocks/CU, 4 waves/SIMD, __launch_bounds__(512,4) -> VGPR cap 128,
// est live ~110).
// vs R16 (19.2us): (1) BOTH kh-variant B-frags precomputed in LDS (32 KB) --
// inner loop is pure ds_read_b128 -> MFMA, no cndmask rebuild on the
// critical path; (2) deferred cross-band consumption: band1's MFMA results
// cross the loop boundary (~150cy gap) and band0's get prefetch+min3
// in between (~55cy), vs R16's ~8cy issue->use gap; acc pairs never overlap
// (a consumed before c issued) so peak regs ~110 < 128.
// Numerics identical to rounds 7-16 (absmax 0.0): K=16 hi/lo bf16 encoding
// folds |q|^2 + |t|^2 - 2q.t into one mfma_f32_32x32x16_bf16;
// C/D row = (r&3) + 8*(r>>2) + 4*kh (verified m74/m101).
// ---------------------------------------------------------------------------
__global__ __launch_bounds__(BLK, 4) void chamfer_partial(
        const float* __restrict__ ori, const float* __restrict__ adv,
        float* __restrict__ rfin) {
    __shared__ uint4 fr[2 * THALF];   // 32 KB: [kh][target]

    int bx = blockIdx.x;               // 0..511
    int half = bx & (NH - 1);
    int rowgroup = (bx >> 2) & (NRG - 1);
    int dirb = bx >> 5;                // 0..15
    int b = dirb & 7;
    int dir = dirb >> 3;

    const float* qsrc = dir ? adv : ori;   // dir0: ori->adv, dir1: adv->ori
    const float* tsrc = dir ? ori : adv;

    // ---- stage this quarter's 1024 targets as BOTH B-frag variants ----
    {
        const float* tx = tsrc + (b * 3 + 0) * NPTS;
        const float* ty = tsrc + (b * 3 + 1) * NPTS;
        const float* tz = tsrc + (b * 3 + 2) * NPTS;
        #pragma unroll
        for (int i = 0; i < THALF / BLK; ++i) {
            int p = threadIdx.x + i * BLK;
            int m = half * THALF + p;
            float x = tx[m], y = ty[m], z = tz[m];
            float n2 = fmaf(x, x, fmaf(y, y, z * z));
            unsigned short hx = f2bf(x), hy = f2bf(y), hz = f2bf(z);
            unsigned short lx = f2bf(x - bf2f(hx));
            unsigned short ly = f2bf(y - bf2f(hy));
            unsigned short lz = f2bf(z - bf2f(hz));
            unsigned short h2 = f2bf(n2);
            unsigned short l2 = f2bf(n2 - bf2f(h2));
            uint4 v0;   // kh=0: B rows 0..7 = [thi(3), tlo(3), n2h, n2l]
            v0.x = (unsigned)hx | ((unsigned)hy << 16);
            v0.y = (unsigned)hz | ((unsigned)lx << 16);
            v0.z = (unsigned)ly | ((unsigned)lz << 16);
            v0.w = (unsigned)h2 | ((unsigned)l2 << 16);
            uint4 v1;   // kh=1: B rows 8..15 = [thi(3), 1, 1, 0,0,0]
            v1.x = v0.x;
            v1.y = (unsigned)hz | (0x3F80u << 16);
            v1.z = 0x00003F80u;
            v1.w = 0u;
            fr[p] = v0;
            fr[THALF + p] = v1;
        }
    }

    // ---- per-wave A fragments: 2 bands of 32 rows ----
    int w = threadIdx.x >> 6;          // wave 0..7
    int l = threadIdx.x & 63;
    int lrow = l & 31;
    int kh = l >> 5;

    short8 afrag0, afrag1;
    #pragma unroll
    for (int bi = 0; bi < 2; ++bi) {
        int q = rowgroup * 512 + (w * 2 + bi) * 32 + lrow;
        float x = qsrc[(b * 3 + 0) * NPTS + q];
        float y = qsrc[(b * 3 + 1) * NPTS + q];
        float z = qsrc[(b * 3 + 2) * NPTS + q];
        float n2 = fmaf(x, x, fmaf(y, y, z * z));
        unsigned short hx = f2bf(x), hy = f2bf(y), hz = f2bf(z);
        unsigned short lx = f2bf(x - bf2f(hx));
        unsigned short ly = f2bf(y - bf2f(hy));
        unsigned short lz = f2bf(z - bf2f(hz));
        unsigned short h2 = f2bf(n2);
        unsigned short l2 = f2bf(n2 - bf2f(h2));
        unsigned short mhx = f2bf(-2.0f * bf2f(hx));
        unsigned short mhy = f2bf(-2.0f * bf2f(hy));
        unsigned short mhz = f2bf(-2.0f * bf2f(hz));
        unsigned short mlx = f2bf(-2.0f * bf2f(lx));
        unsigned short mly = f2bf(-2.0f * bf2f(ly));
        unsigned short mlz = f2bf(-2.0f * bf2f(lz));
        const unsigned short one = 0x3F80;
        union { unsigned short us[8]; short8 s8; } A;
        if (kh == 0) {
            A.us[0] = mhx; A.us[1] = mhy; A.us[2] = mhz;
            A.us[3] = mhx; A.us[4] = mhy; A.us[5] = mhz;
            A.us[6] = one; A.us[7] = one;
        } else {
            A.us[0] = mlx; A.us[1] = mly; A.us[2] = mlz;
            A.us[3] = h2;  A.us[4] = l2;
            A.us[5] = 0;   A.us[6] = 0;   A.us[7] = 0;
        }
        if (bi == 0) afrag0 = A.s8; else afrag1 = A.s8;
    }
    __syncthreads();

    floatx16 zero, rmn0, rmn1;
    #pragma unroll
    for (int r = 0; r < 16; ++r) { zero[r] = 0.0f; rmn0[r] = FLT_MAX; rmn1[r] = FLT_MAX; }

    // per-lane frag pointer: plane kh, column lrow
    const uint4* tp = fr + kh * THALF + lrow;

    // ---- deferred cross-band pipeline over 16 tile-pairs ----
    {
        uint4 f0 = tp[0], f1 = tp[1 << 5];
        // prologue: band0 tile-pair 0
        floatx16 a0 = __builtin_amdgcn_mfma_f32_32x32x16_bf16(afrag0, asS8(f0), zero, 0, 0, 0);
        floatx16 a1 = __builtin_amdgcn_mfma_f32_32x32x16_bf16(afrag0, asS8(f1), zero, 0, 0, 0);
        uint4 fn0 = tp[2 << 5], fn1 = tp[3 << 5];
        #pragma unroll
        for (int r = 0; r < 16; ++r)
            rmn0[r] = fminf(fminf(rmn0[r], a0[r]), a1[r]);   // v_min3
        floatx16 c0 = __builtin_amdgcn_mfma_f32_32x32x16_bf16(afrag1, asS8(f0), zero, 0, 0, 0);
        floatx16 c1 = __builtin_amdgcn_mfma_f32_32x32x16_bf16(afrag1, asS8(f1), zero, 0, 0, 0);
        f0 = fn0; f1 = fn1;

        #pragma unroll 1
        for (int ct = 2; ct < 32; ct += 2) {
            // consume band1 of previous tile-pair (gap ~ full iteration)
            #pragma unroll
            for (int r = 0; r < 16; ++r)
                rmn1[r] = fminf(fminf(rmn1[r], c0[r]), c1[r]);
            // issue band0 of current pair
            a0 = __builtin_amdgcn_mfma_f32_32x32x16_bf16(afrag0, asS8(f0), zero, 0, 0, 0);
            a1 = __builtin_amdgcn_mfma_f32_32x32x16_bf16(afrag0, asS8(f1), zero, 0, 0, 0);
            // prefetch next pair (wraps harmlessly on last iter)
            int nt = (ct + 2) & 31;
            fn0 = tp[nt << 5]; fn1 = tp[(nt + 1) << 5];
            // consume band0 (gap = prefetch issue ~30cy)
            #pragma unroll
            for (int r = 0; r < 16; ++r)
                rmn0[r] = fminf(fminf(rmn0[r], a0[r]), a1[r]);
            // issue band1 of current pair (consumed next iteration)
            c0 = __builtin_amdgcn_mfma_f32_32x32x16_bf16(afrag1, asS8(f0), zero, 0, 0, 0);
            c1 = __builtin_amdgcn_mfma_f32_32x32x16_bf16(afrag1, asS8(f1), zero, 0, 0, 0);
            f0 = fn0; f1 = fn1;
        }
        // epilogue: last band1 pair
        #pragma unroll
        for (int r = 0; r < 16; ++r)
            rmn1[r] = fminf(fminf(rmn1[r], c0[r]), c1[r]);
    }

    // ---- epilogue: register-folding butterfly (17 swizzles/band) ----
    bool b0 = (l & 1), b1 = (l & 2), b2 = (l & 4), b3 = (l & 8);

#define FOLD(v)                                                                \
    {                                                                          \
        _Pragma("unroll")                                                      \
        for (int i = 0; i < 8; ++i) {                                          \
            float send = b0 ? v[i] : v[i + 8];                                 \
            float recv = __shfl_xor(send, 1);                                  \
            v[i] = fminf(b0 ? v[i + 8] : v[i], recv);                          \
        }                                                                      \
        _Pragma("unroll")                                                      \
        for (int i = 0; i < 4; ++i) {                                          \
            float send = b1 ? v[i] : v[i + 4];                                 \
            float recv = __shfl_xor(send, 2);                                  \
            v[i] = fminf(b1 ? v[i + 4] : v[i], recv);                          \
        }                                                                      \
        _Pragma("unroll")                                                      \
        for (int i = 0; i < 2; ++i) {                                          \
            float send = b2 ? v[i] : v[i + 2];                                 \
            float recv = __shfl_xor(send, 4);                                  \
            v[i] = fminf(b2 ? v[i + 2] : v[i], recv);                          \
        }                                                                      \
        {                                                                      \
            float send = b3 ? v[0] : v[1];                                     \
            float recv = __shfl_xor(send, 8);                                  \
            v[0] = fminf(b3 ? v[1] : v[0], recv);                              \
        }                                                                      \
        v[0] = fminf(v[0], __shfl_xor(v[0], 16));                              \
    }

    FOLD(rmn0);
    FOLD(rmn1);
#undef FOLD

    // lane g = l&15 holds reg rr = bitrev4(g); row-in-band = (rr&3)+8*(rr>>2)+4*kh
    if ((l & 16) == 0) {
        int g = l & 15;
        int rr = ((g & 1) << 3) | ((g & 2) << 1) | ((g & 4) >> 1) | ((g & 8) >> 3);
        int rowin = (rr & 3) + 8 * (rr >> 2) + 4 * kh;
        float* base = rfin + (((size_t)(dirb * NH + half)) << 12)
                    + rowgroup * 512;
        base[(w * 2 + 0) * 32 + rowin] = rmn0[0];
        base[(w * 2 + 1) * 32 + rowin] = rmn1[0];
    }
}

// ---------------------------------------------------------------------------
// Combine: 64 blocks = (dirb(16), slice(4)). Each thread: 4 rows, min over
// the 4 quarter planes, clamp >=0, fixed-order sum -> pb[cb] + token flag.
// Block 0 spins on all 64 flags (R9/R12-proven; 64 blocks trivially
// co-resident) and finalizes out[0]. Bit-identical every replay.
// ---------------------------------------------------------------------------
__global__ __launch_bounds__(256) void combine_kernel(
        const float* __restrict__ rfin, float* __restrict__ pb,
        unsigned* __restrict__ flags, float* __restrict__ out) {
    __shared__ float ws[4];
    __shared__ float sh[64 + 16];
    int cb = blockIdx.x;               // 0..63
    int dirb = cb >> 2, slice = cb & 3;
    const float* p = rfin + (((size_t)dirb * NH) << 12);
    float s = 0.0f;
    #pragma unroll
    for (int k = 0; k < 4; ++k) {
        int row = slice * 1024 + k * 256 + threadIdx.x;
        float m = fminf(fminf(p[row], p[(1 << 12) + row]),
                        fminf(p[(2 << 12) + row], p[(3 << 12) + row]));
        s += fmaxf(m, 0.0f);
    }
    for (int off = 32; off > 0; off >>= 1) s += __shfl_down(s, off);
    int wid = threadIdx.x >> 6, lane = threadIdx.x & 63;
    if (lane == 0) ws[wid] = s;
    __syncthreads();
    if (threadIdx.x == 0) {
        float t = ws[0] + ws[1] + ws[2] + ws[3];
        atomicExch((unsigned*)(pb + cb), __float_as_uint(t));
        __threadfence();
        atomicExch(flags + cb, flag_token(cb));
    }

    if (cb == 0) {
        __syncthreads();
        int t = threadIdx.x;
        if (t < 64) {
            unsigned want = flag_token(t);
            while (atomicAdd(flags + t, 0u) != want) {
                __builtin_amdgcn_s_sleep(1);
            }
            sh[t] = __uint_as_float(atomicAdd((unsigned*)(pb + t), 0u));
        }
        __syncthreads();
        if (t < 16) {
            sh[64 + t] = sh[t * 4] + sh[t * 4 + 1] + sh[t * 4 + 2] + sh[t * 4 + 3];
        }
        __syncthreads();
        if (t == 0) {
            float acc = 0.0f;
            #pragma unroll
            for (int bb = 0; bb < BATCH; ++bb)
                acc += fmaxf(sh[64 + bb], sh[64 + 8 + bb]);
            out[0] = acc * (1.0f / (float)NPTS) * (1.0f / (float)BATCH);
        }
    }
}

extern "C" void kernel_launch(void* const* d_in, const int* in_sizes, int n_in,
                              void* d_out, int out_size, void* d_ws, size_t ws_size,
                              hipStream_t stream) {
    const float* ori = (const float*)d_in[0];
    const float* adv = (const float*)d_in[1];
    float* out = (float*)d_out;

    // ws: rfin[16 dirb][4 quarter][4096 row] floats (1 MB) | pb[64] | flags[64]
    float* rfin = (float*)d_ws;
    float* pb = rfin + (size_t)16 * NH * NPTS;
    unsigned* flags = (unsigned*)(pb + 64);

    chamfer_partial<<<16 * NRG * NH, BLK, 0, stream>>>(ori, adv, rfin);
    combine_kernel<<<64, 256, 0, stream>>>(rfin, pb, flags, out);
}